// Round 7
// baseline (286.641 us; speedup 1.0000x reference)
//
#include <hip/hip_runtime.h>

typedef float v2f __attribute__((ext_vector_type(2)));
typedef float v4f __attribute__((ext_vector_type(4)));

#define DD   187   // input dim
#define HH   50    // hidden
#define PH   64    // LDS padded hidden (4 lanes x 16 slots)
#define HPJ  14    // hidden neurons per lane (logical)
#define HPL  16    // LDS slots per lane (64B -> b128-aligned reads)
#define NP   7     // float2 pairs per lane
#define NC   5     // classes
#define RPB  64    // rows per block = 32 quads x 2 rows
#define BLK  128   // 2 waves/block; 512 blocks -> 1 wave/SIMD, 2 blocks/CU
#define DCH  32    // d-chunk
#define NCHUNK 6   // ceil(187/32)
#define XSS  44    // xs row stride: 176B = 16B-aligned, odd-ish bank spread
#define BETA 0.9f

__device__ __forceinline__ float dpp_xor1(float v) {
    // quad_perm [1,0,3,2] -> lane^1
    return __builtin_bit_cast(float,
        __builtin_amdgcn_mov_dpp(__builtin_bit_cast(int, v), 0xB1, 0xF, 0xF, true));
}
__device__ __forceinline__ float dpp_xor2(float v) {
    // quad_perm [2,3,0,1] -> lane^2
    return __builtin_bit_cast(float,
        __builtin_amdgcn_mov_dpp(__builtin_bit_cast(int, v), 0x4E, 0xF, 0xF, true));
}

__device__ __forceinline__ float spike1(float m) {
    // exact (m > 1) ? 1 : 0 : fma(m,2^60,-2^60) > 0 iff m>1 (f32), med3-clamp [0,1]
    float t = fmaf(m, 0x1.0p60f, -0x1.0p60f);
    return __builtin_amdgcn_fmed3f(t, 0.f, 1.f);
}
__device__ __forceinline__ v2f spike2(v2f m) {
    const v2f BIG2  = { 0x1.0p60f,  0x1.0p60f};
    const v2f NBIG2 = {-0x1.0p60f, -0x1.0p60f};
    v2f t = __builtin_elementwise_fma(m, BIG2, NBIG2);
    v2f s;
    s.x = __builtin_amdgcn_fmed3f(t.x, 0.f, 1.f);
    s.y = __builtin_amdgcn_fmed3f(t.y, 0.f, 1.f);
    return s;
}

__device__ __forceinline__ v2f vlo(v4f v) { return __builtin_shufflevector(v, v, 0, 1); }
__device__ __forceinline__ v2f vhi(v4f v) { return __builtin_shufflevector(v, v, 2, 3); }

// 2 rows per quad: halves wave count (1024 waves = 1/SIMD) and doubles per-wave
// ILP; W2 fragments (70 VGPR) shared across both recurrences. waves_per_eu(1,1)
// -> full 256-VGPR budget for the ~200-reg live set.
__global__ __launch_bounds__(BLK, 1) __attribute__((amdgpu_waves_per_eu(1, 1)))
void snn_kernel(const float* __restrict__ x,
                const float* __restrict__ W1,
                const float* __restrict__ b1,
                const float* __restrict__ W2,
                const float* __restrict__ b2,
                const int*   __restrict__ nsp,
                float* __restrict__ out, int Brows)
{
    __shared__ __align__(16) float xs[RPB * XSS];   // 11,264 B
    __shared__ __align__(16) float w1t[DCH * PH];   //  8,192 B (d-major, 4x16 slots)

    const int tid  = threadIdx.x;
    const int p    = tid >> 2;        // quad id 0..31 -> owns rows 2p, 2p+1
    const int k    = tid & 3;         // lane within quad: hidden slice + class owner
    const int row0 = blockIdx.x * RPB + 2 * p;
    const int NS   = nsp[0];

    // ---------------- Phase 1: cur1 = x @ W1^T for BOTH rows (chunked over d) ---
    // Weight fragment (56B/lane/d) now amortized across 2 rows -> per-CU LDS
    // traffic ~5.5 MB -> ~3.1 MB (phase 1 was LDS-return-BW bound, ~27us).
    v2f acca[NP], accb[NP];
#pragma unroll
    for (int i = 0; i < NP; ++i) { acca[i] = (v2f){0.f, 0.f}; accb[i] = (v2f){0.f, 0.f}; }

    for (int ch = 0; ch < NCHUNK; ++ch) {
        const int d0 = ch * DCH;
        for (int i = tid; i < RPB * DCH; i += BLK) {
            int r = i >> 5, dd = i & 31;
            int d = d0 + dd;
            xs[r * XSS + dd] = (d < DD) ? x[(size_t)(blockIdx.x * RPB + r) * DD + d] : 0.f;
        }
        // conflict-free staging: consecutive threads -> consecutive LDS addresses.
        // slot s = kk*16 + j holds logical hidden h = kk*14 + j (j<14), pads zero.
        for (int i = tid; i < DCH * PH; i += BLK) {
            int dd = i >> 6, s = i & 63;
            int kk = s >> 4, j = s & 15;
            int h = kk * HPJ + j;
            int d = d0 + dd;
            w1t[dd * PH + s] = (j < HPJ && h < HH && d < DD) ? W1[h * DD + d] : 0.f;
        }
        __syncthreads();

        const float* xr0 = xs + (2 * p)     * XSS;
        const float* xr1 = xs + (2 * p + 1) * XSS;
#pragma unroll 2
        for (int d4 = 0; d4 < DCH / 4; ++d4) {
            v4f xa4 = *(const v4f*)(xr0 + 4 * d4);
            v4f xb4 = *(const v4f*)(xr1 + 4 * d4);
#pragma unroll
            for (int j = 0; j < 4; ++j) {
                int d = 4 * d4 + j;
                const float* wbase = w1t + d * PH + k * HPL;   // 64B aligned per lane
                v4f w0 = *(const v4f*)(wbase);
                v4f w1v = *(const v4f*)(wbase + 4);
                v4f w2v = *(const v4f*)(wbase + 8);
                v2f w3 = *(const v2f*)(wbase + 12);            // pairs (12,13)
                v2f xa = {xa4[j], xa4[j]};
                v2f xb = {xb4[j], xb4[j]};
                acca[0] = __builtin_elementwise_fma(xa, vlo(w0),  acca[0]);
                accb[0] = __builtin_elementwise_fma(xb, vlo(w0),  accb[0]);
                acca[1] = __builtin_elementwise_fma(xa, vhi(w0),  acca[1]);
                accb[1] = __builtin_elementwise_fma(xb, vhi(w0),  accb[1]);
                acca[2] = __builtin_elementwise_fma(xa, vlo(w1v), acca[2]);
                accb[2] = __builtin_elementwise_fma(xb, vlo(w1v), accb[2]);
                acca[3] = __builtin_elementwise_fma(xa, vhi(w1v), acca[3]);
                accb[3] = __builtin_elementwise_fma(xb, vhi(w1v), accb[3]);
                acca[4] = __builtin_elementwise_fma(xa, vlo(w2v), acca[4]);
                accb[4] = __builtin_elementwise_fma(xb, vlo(w2v), accb[4]);
                acca[5] = __builtin_elementwise_fma(xa, vhi(w2v), acca[5]);
                accb[5] = __builtin_elementwise_fma(xb, vhi(w2v), accb[5]);
                acca[6] = __builtin_elementwise_fma(xa, w3,       acca[6]);
                accb[6] = __builtin_elementwise_fma(xb, w3,       accb[6]);
            }
        }
        __syncthreads();
    }

    // cur1 = acc + b1 for both rows (pads stay 0 -> padded neurons never spike)
    v2f c1a[NP], c1b[NP];
#pragma unroll
    for (int i = 0; i < NP; ++i) {
        int h0 = k * HPJ + 2 * i;
        v2f bb;
        bb.x = (h0     < HH) ? b1[h0]     : 0.f;
        bb.y = (h0 + 1 < HH) ? b1[h0 + 1] : 0.f;
        c1a[i] = acca[i] + bb;
        c1b[i] = accb[i] + bb;
    }
    // bias neuron: pad slot h=55 (k=3, pair 6, .y) fires every step (m: 2 -> 10, >1),
    // its W2 column is b2 -> cur2 arrives with bias already included (all 5 classes).
    if (k == 3) { c1a[6].y = 2.0f; c1b[6].y = 2.0f; }

    // W2 fragments (70 VGPRs) — shared by BOTH recurrences
    v2f w2r[NC][NP];
#pragma unroll
    for (int c = 0; c < NC; ++c)
#pragma unroll
        for (int i = 0; i < NP; ++i) {
            int h0 = k * HPJ + 2 * i;
            w2r[c][i].x = (h0     < HH) ? W2[c * HH + h0]     : 0.f;
            w2r[c][i].y = (h0 + 1 < HH) ? W2[c * HH + h0 + 1] : 0.f;
        }
    if (k == 3) {
#pragma unroll
        for (int c = 0; c < NC; ++c) w2r[c][6].y = b2[c];
    }

    // ---------------- Phase 2: 100-step LIF recurrence, 2 rows in flight --------
    v2f m1a[NP], s1a[NP], m1b[NP], s1b[NP];
#pragma unroll
    for (int i = 0; i < NP; ++i) {
        m1a[i] = (v2f){0.f, 0.f}; s1a[i] = (v2f){0.f, 0.f};
        m1b[i] = (v2f){0.f, 0.f}; s1b[i] = (v2f){0.f, 0.f};
    }
    float mA0 = 0.f, sA0 = 0.f, mB0 = 0.f, sB0 = 0.f;
    float mA1 = 0.f, sA1 = 0.f, mB1 = 0.f, sB1 = 0.f;

    const size_t stride = (size_t)Brows * NC;
    float* spkBase = out;                          // + t*stride each step (wave-uniform)
    float* memBase = out + (size_t)NS * stride;
    const int offA0 = row0 * NC + k;               // row 2p,   lanes k=0..3 consecutive
    const int offA1 = offA0 + NC;                  // row 2p+1
    const int offB0 = row0 * NC + 4;
    const int offB1 = offB0 + NC;
    const v2f BETA2 = {BETA, BETA};
    const v2f ZERO2 = {0.f, 0.f};

    v2f cpa[NC], cpb[NC];
    // advance BOTH rows' layer-1 one step; produce fresh class partials cpa/cpb.
    // a/b interleaved -> 2 independent chains per op class (ILP).
    auto S1 = [&]() {
#pragma unroll
        for (int c = 0; c < NC; ++c) { cpa[c] = ZERO2; cpb[c] = ZERO2; }
#pragma unroll
        for (int i = 0; i < NP; ++i) {
            v2f ma = __builtin_elementwise_fma(BETA2, m1a[i], c1a[i]) - s1a[i];
            v2f mb = __builtin_elementwise_fma(BETA2, m1b[i], c1b[i]) - s1b[i];
            m1a[i] = ma; m1b[i] = mb;
            v2f sa = spike2(ma);
            v2f sb = spike2(mb);
            s1a[i] = sa; s1b[i] = sb;
#pragma unroll
            for (int c = 0; c < NC; ++c) {
                cpa[c] = __builtin_elementwise_fma(sa, w2r[c][i], cpa[c]);
                cpb[c] = __builtin_elementwise_fma(sb, w2r[c][i], cpb[c]);
            }
        }
    };

    S1();   // cp for t = 0
    for (int t = 0; t < NS; ++t) {
        // quad butterfly reductions for both rows (independent DPP chains)
        float cur2a[NC], cur2b[NC];
#pragma unroll
        for (int c = 0; c < NC; ++c) {
            float ra = cpa[c].x + cpa[c].y;
            float rb = cpb[c].x + cpb[c].y;
            ra += dpp_xor1(ra);  rb += dpp_xor1(rb);
            ra += dpp_xor2(ra);  rb += dpp_xor2(rb);
            cur2a[c] = ra; cur2b[c] = rb;
        }
        // layer-1 of step t+1 — independent of cur2; fills stall slots below.
        // (extra run on the last step touches no memory; harmless)
        S1();

        float cA0 = (k == 1) ? cur2a[1] : (k == 2) ? cur2a[2] :
                    (k == 3) ? cur2a[3] : cur2a[0];
        float cA1 = (k == 1) ? cur2b[1] : (k == 2) ? cur2b[2] :
                    (k == 3) ? cur2b[3] : cur2b[0];
        float cB0 = cur2a[4];
        float cB1 = cur2b[4];

        mA0 = fmaf(BETA, mA0, cA0) - sA0;  sA0 = spike1(mA0);   // b2 folded via bias neuron
        mA1 = fmaf(BETA, mA1, cA1) - sA1;  sA1 = spike1(mA1);
        mB0 = fmaf(BETA, mB0, cB0) - sB0;  sB0 = spike1(mB0);
        mB1 = fmaf(BETA, mB1, cB1) - sB1;  sB1 = spike1(mB1);

        spkBase[offA0] = sA0;
        spkBase[offA1] = sA1;
        memBase[offA0] = mA0;
        memBase[offA1] = mA1;
        if (k == 0) {
            spkBase[offB0] = sB0;  spkBase[offB1] = sB1;
            memBase[offB0] = mB0;  memBase[offB1] = mB1;
        }

        spkBase += stride;
        memBase += stride;
    }
}

extern "C" void kernel_launch(void* const* d_in, const int* in_sizes, int n_in,
                              void* d_out, int out_size, void* d_ws, size_t ws_size,
                              hipStream_t stream) {
    const float* x  = (const float*)d_in[0];
    const float* W1 = (const float*)d_in[1];
    const float* b1 = (const float*)d_in[2];
    const float* W2 = (const float*)d_in[3];
    const float* b2 = (const float*)d_in[4];
    const int*   ns = (const int*)d_in[5];
    int B = in_sizes[0] / DD;          // 32768
    int nblocks = B / RPB;             // 512 blocks x 2 waves = 1024 waves, 2 blk/CU
    snn_kernel<<<nblocks, BLK, 0, stream>>>(x, W1, b1, W2, b2, ns, (float*)d_out, B);
}

// Round 8
// 231.427 us; speedup vs baseline: 1.2386x; 1.2386x over previous
//
#include <hip/hip_runtime.h>

typedef float v2f __attribute__((ext_vector_type(2)));
typedef float v4f __attribute__((ext_vector_type(4)));

#define DD   187   // input dim
#define HH   50    // hidden
#define PH   64    // LDS padded hidden (4 lanes x 16 slots)
#define HPJ  14    // hidden neurons per lane (logical)
#define HPL  16    // LDS slots per lane (64B -> b128-aligned reads)
#define NP   7     // float2 pairs per lane
#define NC   5     // classes
#define RPB  64    // rows per block (4 lanes/row in phase 2, 256 threads)
#define BLK  256
#define DCH  64    // d-chunk
#define NCHUNK 3   // ceil(187/64)
#define XSS  68    // xs row stride (mult of 4 -> 16B-aligned v4f reads)
#define BETA 0.9f

__device__ __forceinline__ float dpp_xor1(float v) {
    // quad_perm [1,0,3,2] -> lane^1
    return __builtin_bit_cast(float,
        __builtin_amdgcn_mov_dpp(__builtin_bit_cast(int, v), 0xB1, 0xF, 0xF, true));
}
__device__ __forceinline__ float dpp_xor2(float v) {
    // quad_perm [2,3,0,1] -> lane^2
    return __builtin_bit_cast(float,
        __builtin_amdgcn_mov_dpp(__builtin_bit_cast(int, v), 0x4E, 0xF, 0xF, true));
}

__device__ __forceinline__ float spike1(float m) {
    // exact (m > 1) ? 1 : 0 : fma(m,2^60,-2^60) > 0 iff m>1 (f32), med3-clamp [0,1]
    float t = fmaf(m, 0x1.0p60f, -0x1.0p60f);
    return __builtin_amdgcn_fmed3f(t, 0.f, 1.f);
}
__device__ __forceinline__ v2f spike2(v2f m) {
    const v2f BIG2  = { 0x1.0p60f,  0x1.0p60f};
    const v2f NBIG2 = {-0x1.0p60f, -0x1.0p60f};
    v2f t = __builtin_elementwise_fma(m, BIG2, NBIG2);
    v2f s;
    s.x = __builtin_amdgcn_fmed3f(t.x, 0.f, 1.f);
    s.y = __builtin_amdgcn_fmed3f(t.y, 0.f, 1.f);
    return s;
}

__device__ __forceinline__ v2f vlo(v4f v) { return __builtin_shufflevector(v, v, 0, 1); }
__device__ __forceinline__ v2f vhi(v4f v) { return __builtin_shufflevector(v, v, 2, 3); }

// Structural occupancy is 2 waves/SIMD (2048 waves / 1024 SIMDs).
__global__ __launch_bounds__(BLK, 2) __attribute__((amdgpu_waves_per_eu(2, 2)))
void snn_kernel(const float* __restrict__ x,
                const float* __restrict__ W1,
                const float* __restrict__ b1,
                const float* __restrict__ W2,
                const float* __restrict__ b2,
                const int*   __restrict__ nsp,
                float* __restrict__ out, int Brows)
{
    __shared__ __align__(16) float xs[RPB * XSS];   // 17,408 B
    __shared__ __align__(16) float w1t[DCH * PH];   // 16,384 B (d-major, 4x16 slots)
    float* cbuf = w1t;   // redistribution buffer (3,584 B) overlays dead w1t

    const int tid = threadIdx.x;
    const int p   = tid >> 2;         // phase-2: row within block (quad id)
    const int k   = tid & 3;          // lane within quad: hidden slice + class owner
    const int row = blockIdx.x * RPB + p;
    const int NS  = nsp[0];

    // ---------------- Phase 1: cur1 = x @ W1^T, 2 rows per working thread -------
    // r7 proved the 2-rows amortization halves phase-1 LDS traffic (P1 ~29 -> ~15us)
    // but its phase-2 geometry cost 2x. Decouple: 128 working threads compute 2 rows
    // each (same per-row d-order -> bit-identical), idle waves park at the barrier,
    // then redistribute cur1 via LDS into the phase-2 1-row/quad ownership.
    const int pr = tid >> 2;          // working-thread row-pair id 0..31 (tid<128)
    v2f acca[NP], accb[NP];
#pragma unroll
    for (int i = 0; i < NP; ++i) { acca[i] = (v2f){0.f, 0.f}; accb[i] = (v2f){0.f, 0.f}; }

    for (int ch = 0; ch < NCHUNK; ++ch) {
        const int d0 = ch * DCH;
        for (int i = tid; i < RPB * DCH; i += BLK) {
            int r = i >> 6, dd = i & 63;
            int d = d0 + dd;
            xs[r * XSS + dd] = (d < DD) ? x[(size_t)(blockIdx.x * RPB + r) * DD + d] : 0.f;
        }
        // conflict-free staging: consecutive threads -> consecutive LDS addresses.
        // slot s = kk*16 + j holds logical hidden h = kk*14 + j (j<14), pads zero.
        for (int i = tid; i < DCH * PH; i += BLK) {
            int dd = i >> 6, s = i & 63;
            int kk = s >> 4, j = s & 15;
            int h = kk * HPJ + j;
            int d = d0 + dd;
            w1t[dd * PH + s] = (j < HPJ && h < HH && d < DD) ? W1[h * DD + d] : 0.f;
        }
        __syncthreads();

        if (tid < 128) {   // wave-uniform guard (waves 0,1 work; 2,3 park)
            const float* xr0 = xs + (2 * pr)     * XSS;
            const float* xr1 = xs + (2 * pr + 1) * XSS;
#pragma unroll 2
            for (int d4 = 0; d4 < DCH / 4; ++d4) {
                v4f xa4 = *(const v4f*)(xr0 + 4 * d4);
                v4f xb4 = *(const v4f*)(xr1 + 4 * d4);
#pragma unroll
                for (int j = 0; j < 4; ++j) {
                    int d = 4 * d4 + j;
                    const float* wbase = w1t + d * PH + k * HPL;   // 64B aligned
                    v4f w0 = *(const v4f*)(wbase);
                    v4f w1v = *(const v4f*)(wbase + 4);
                    v4f w2v = *(const v4f*)(wbase + 8);
                    v2f w3 = *(const v2f*)(wbase + 12);            // pairs (12,13)
                    v2f xa = {xa4[j], xa4[j]};
                    v2f xb = {xb4[j], xb4[j]};
                    acca[0] = __builtin_elementwise_fma(xa, vlo(w0),  acca[0]);
                    accb[0] = __builtin_elementwise_fma(xb, vlo(w0),  accb[0]);
                    acca[1] = __builtin_elementwise_fma(xa, vhi(w0),  acca[1]);
                    accb[1] = __builtin_elementwise_fma(xb, vhi(w0),  accb[1]);
                    acca[2] = __builtin_elementwise_fma(xa, vlo(w1v), acca[2]);
                    accb[2] = __builtin_elementwise_fma(xb, vlo(w1v), accb[2]);
                    acca[3] = __builtin_elementwise_fma(xa, vhi(w1v), acca[3]);
                    accb[3] = __builtin_elementwise_fma(xb, vhi(w1v), accb[3]);
                    acca[4] = __builtin_elementwise_fma(xa, vlo(w2v), acca[4]);
                    accb[4] = __builtin_elementwise_fma(xb, vlo(w2v), accb[4]);
                    acca[5] = __builtin_elementwise_fma(xa, vhi(w2v), acca[5]);
                    accb[5] = __builtin_elementwise_fma(xb, vhi(w2v), accb[5]);
                    acca[6] = __builtin_elementwise_fma(xa, w3,       acca[6]);
                    accb[6] = __builtin_elementwise_fma(xb, w3,       accb[6]);
                }
            }
        }
        __syncthreads();
    }

    // redistribute: working thread holds rows (2pr, 2pr+1) slice k -> phase-2 owner
    // thread (row*4+k). One LDS round-trip, bit-preserving.
    if (tid < 128) {
#pragma unroll
        for (int i = 0; i < NP; ++i) {
            *(v2f*)(cbuf + (2 * pr)     * 56 + k * HPJ + 2 * i) = acca[i];
            *(v2f*)(cbuf + (2 * pr + 1) * 56 + k * HPJ + 2 * i) = accb[i];
        }
    }
    __syncthreads();

    // cur1 = acc + b1 (pads stay 0 -> padded neurons never spike)
    v2f c1[NP];
#pragma unroll
    for (int i = 0; i < NP; ++i) {
        int h0 = k * HPJ + 2 * i;
        v2f bb;
        bb.x = (h0     < HH) ? b1[h0]     : 0.f;
        bb.y = (h0 + 1 < HH) ? b1[h0 + 1] : 0.f;
        c1[i] = *(const v2f*)(cbuf + p * 56 + k * HPJ + 2 * i) + bb;
    }
    // bias neuron: pad slot h=55 (k=3, pair 6, .y) fires every step (m: 2 -> 10, >1),
    // its W2 column is b2 -> cur2 arrives with bias already included (all 5 classes).
    if (k == 3) c1[6].y = 2.0f;

    // W2 fragments (70 VGPRs). FETCH_SIZE across rounds proves these load once.
    v2f w2r[NC][NP];
#pragma unroll
    for (int c = 0; c < NC; ++c)
#pragma unroll
        for (int i = 0; i < NP; ++i) {
            int h0 = k * HPJ + 2 * i;
            w2r[c][i].x = (h0     < HH) ? W2[c * HH + h0]     : 0.f;
            w2r[c][i].y = (h0 + 1 < HH) ? W2[c * HH + h0 + 1] : 0.f;
        }
    if (k == 3) {
#pragma unroll
        for (int c = 0; c < NC; ++c) w2r[c][6].y = b2[c];
    }

    // keep w2r/c1 opaque (no in-loop remat) — neutral in r3, retained for stability
#pragma unroll
    for (int c = 0; c < NC; ++c) {
        asm volatile("" : "+v"(w2r[c][0]), "+v"(w2r[c][1]), "+v"(w2r[c][2]),
                          "+v"(w2r[c][3]), "+v"(w2r[c][4]), "+v"(w2r[c][5]),
                          "+v"(w2r[c][6]));
    }
    asm volatile("" : "+v"(c1[0]), "+v"(c1[1]), "+v"(c1[2]), "+v"(c1[3]),
                      "+v"(c1[4]), "+v"(c1[5]), "+v"(c1[6]));

    // ---------------- Phase 2: 100-step LIF recurrence (r3 verbatim) ------------
    v2f m1[NP], s1[NP];
#pragma unroll
    for (int i = 0; i < NP; ++i) { m1[i] = (v2f){0.f, 0.f}; s1[i] = (v2f){0.f, 0.f}; }
    float mA = 0.f, sA = 0.f, mB = 0.f, sB = 0.f;

    const size_t stride = (size_t)Brows * NC;
    float* spkBase = out;                          // + t*stride each step (wave-uniform)
    float* memBase = out + (size_t)NS * stride;
    const int offA = row * NC + k;                 // lanes k=0..3 -> 4 consecutive dwords
    const int offB = row * NC + 4;
    const v2f BETA2 = {BETA, BETA};
    const v2f ZERO2 = {0.f, 0.f};

    v2f cp[NC];
    // layer-1 step: advance m1/s1 one step and produce fresh class partials cp
    auto S1 = [&]() {
#pragma unroll
        for (int c = 0; c < NC; ++c) cp[c] = ZERO2;
#pragma unroll
        for (int i = 0; i < NP; ++i) {
            v2f m = __builtin_elementwise_fma(BETA2, m1[i], c1[i]) - s1[i];
            m1[i] = m;
            v2f s = spike2(m);
            s1[i] = s;
#pragma unroll
            for (int c = 0; c < NC; ++c)
                cp[c] = __builtin_elementwise_fma(s, w2r[c][i], cp[c]);
        }
    };

    S1();   // cp for t = 0
#pragma unroll 2
    for (int t = 0; t < NS; ++t) {
        // quad butterfly reduction of step t's partials
        float cur2[NC];
#pragma unroll
        for (int c = 0; c < NC; ++c) {
            float r = cp[c].x + cp[c].y;
            r += dpp_xor1(r);
            r += dpp_xor2(r);
            cur2[c] = r;
        }
        // layer-1 of step t+1 — independent of cur2; fills stall slots below.
        // (extra run on the last step touches no memory; harmless)
        S1();

        float cA = (k == 1) ? cur2[1] : (k == 2) ? cur2[2] :
                   (k == 3) ? cur2[3] : cur2[0];
        float cB = cur2[4];

        mA = fmaf(BETA, mA, cA) - sA;   // b2 folded in via bias neuron
        sA = spike1(mA);
        mB = fmaf(BETA, mB, cB) - sB;
        sB = spike1(mB);

        spkBase[offA] = sA;                   // 4 consecutive dwords per quad
        memBase[offA] = mA;
        if (k == 0) { spkBase[offB] = sB; memBase[offB] = mB; }

        spkBase += stride;
        memBase += stride;
    }
}

extern "C" void kernel_launch(void* const* d_in, const int* in_sizes, int n_in,
                              void* d_out, int out_size, void* d_ws, size_t ws_size,
                              hipStream_t stream) {
    const float* x  = (const float*)d_in[0];
    const float* W1 = (const float*)d_in[1];
    const float* b1 = (const float*)d_in[2];
    const float* W2 = (const float*)d_in[3];
    const float* b2 = (const float*)d_in[4];
    const int*   ns = (const int*)d_in[5];
    int B = in_sizes[0] / DD;          // 32768
    int nblocks = B / RPB;             // 512 -> 2 blocks/CU, 8 waves/CU
    snn_kernel<<<nblocks, BLK, 0, stream>>>(x, W1, b1, W2, b2, ns, (float*)d_out, B);
}